// Round 1
// baseline (3386.644 us; speedup 1.0000x reference)
//
#include <hip/hip_runtime.h>
#include <hip/hip_bf16.h>

// Sizes from the reference
#define NSEQ   32
#define SEQLEN 256
#define NB     16    // batch
#define NIN    32
#define NH     256
#define G4     1024  // 4*H

typedef __attribute__((ext_vector_type(8))) short bf16x8;
typedef __attribute__((ext_vector_type(4))) float f32x4;

__device__ __forceinline__ unsigned short f2bf(float f) {
    union { float f; unsigned u; } v; v.f = f;
    unsigned u = v.u;
    return (unsigned short)((u + 0x7FFFu + ((u >> 16) & 1u)) >> 16);  // RNE
}
__device__ __forceinline__ float sigf(float x) { return 1.0f / (1.0f + __expf(-x)); }
__device__ __forceinline__ float tanhfast(float x) { return 1.0f - 2.0f / (__expf(2.0f * x) + 1.0f); }

// ---------------- Prologue: pack weights into MFMA B-fragment layout ----------------
// Layer1: W'[fl][n][k], k<256 -> Whh1[fl][n][k], k>=256 -> Wih1[fl][n][k-256]
// B_packed[((fl*64+tile)*9+kk)*64 + lane][j] = bf16(W'[fl][tile*16+(l&15)][kk*32+(l>>4)*8+j])
__global__ void pack_w1(const float* __restrict__ Wih, const float* __restrict__ Whh,
                        unsigned short* __restrict__ Bp) {
    int idx = blockIdx.x * blockDim.x + threadIdx.x;
    if (idx >= 2 * 64 * 9 * 64) return;
    int fl   = idx / (64 * 9 * 64);
    int rem  = idx % (64 * 9 * 64);
    int tile = rem / (9 * 64);
    int kk   = (rem / 64) % 9;
    int l    = rem & 63;
    int n    = tile * 16 + (l & 15);
    int k0   = kk * 32 + (l >> 4) * 8;
    unsigned short* dst = Bp + (size_t)idx * 8;
#pragma unroll
    for (int j = 0; j < 8; ++j) {
        int k = k0 + j;
        float v = (k < NH) ? Whh[((size_t)fl * G4 + n) * NH + k]
                           : Wih[((size_t)fl * G4 + n) * NIN + (k - NH)];
        dst[j] = f2bf(v);
    }
}

// Layer2: W2'[n][k], k<256 -> Whh2[n][k], k>=256 -> Wih2[n][k-256]; 16 kk groups (K=512)
__global__ void pack_w2(const float* __restrict__ Wih, const float* __restrict__ Whh,
                        unsigned short* __restrict__ Bp) {
    int idx = blockIdx.x * blockDim.x + threadIdx.x;
    if (idx >= 64 * 16 * 64) return;
    int tile = idx / (16 * 64);
    int kk   = (idx / 64) % 16;
    int l    = idx & 63;
    int n    = tile * 16 + (l & 15);
    int k0   = kk * 32 + (l >> 4) * 8;
    unsigned short* dst = Bp + (size_t)idx * 8;
#pragma unroll
    for (int j = 0; j < 8; ++j) {
        int k = k0 + j;
        float v = (k < NH) ? Whh[(size_t)n * NH + k] : Wih[(size_t)n * NH + (k - NH)];
        dst[j] = f2bf(v);
    }
}

// ---------------- Layer 1: 32 independent 256-step LSTM scans ----------------
// 1 block per sequence, 1024 threads = 16 waves. Wave w owns gate-tiles {g*16+w},
// i.e. columns m = w*16 + (l&15) of all 4 gates -> cell update fully in registers.
#define STRA 296  // A_sh row stride in bf16 (288 data + 8 pad for bank spread)

__global__ __launch_bounds__(1024) void lstm_layer1(
    const float* __restrict__ x, const int* __restrict__ flags,
    const float* __restrict__ bih, const float* __restrict__ bhh,
    const unsigned short* __restrict__ Bp_all,
    unsigned short* __restrict__ h1bf) {
    __shared__ __align__(16) unsigned short A_sh[NB * STRA];  // [h(256) | x(32)] bf16 per batch row

    const int s   = blockIdx.x;
    const int tid = threadIdx.x;
    const int w   = tid >> 6;
    const int l   = tid & 63;
    const int lr  = l & 15;    // A-fragment row (= batch), and column-in-tile
    const int kg  = l >> 4;    // k-group for A/B frags; D rows kg*4..kg*4+3
    const int fl  = flags[s];
    const unsigned short* Bp = Bp_all + (size_t)fl * (64 * 9 * 64 * 8);
    const int m = w * 16 + lr;  // hidden column owned by this lane

    float bias[4];
#pragma unroll
    for (int g = 0; g < 4; ++g)
        bias[g] = bih[fl * G4 + g * NH + m] + bhh[fl * G4 + g * NH + m];

    float c[4] = {0.f, 0.f, 0.f, 0.f};  // cell state for (batch kg*4+r, column m)

    // init: h = 0
    for (int i = tid; i < NB * NH; i += 1024)
        A_sh[(i >> 8) * STRA + (i & 255)] = 0;
    // x for t=0
    if (tid < NB * NIN) {
        int b = tid >> 5, k = tid & 31;
        A_sh[b * STRA + NH + k] = f2bf(x[((size_t)(s * SEQLEN) * NB + b) * NIN + k]);
    }
    __syncthreads();

    const int xb = tid >> 5, xk = tid & 31;
    for (int t = 0; t < SEQLEN; ++t) {
        // prefetch next step's x (consumed after the barrier, overlaps MFMA)
        float xpre = 0.f;
        if (t + 1 < SEQLEN && tid < NB * NIN)
            xpre = x[((size_t)(s * SEQLEN + t + 1) * NB + xb) * NIN + xk];

        f32x4 acc[4];
#pragma unroll
        for (int g = 0; g < 4; ++g) { f32x4 v = {bias[g], bias[g], bias[g], bias[g]}; acc[g] = v; }

#pragma unroll
        for (int kk = 0; kk < 9; ++kk) {
            bf16x8 a = *(const bf16x8*)&A_sh[lr * STRA + kk * 32 + kg * 8];
#pragma unroll
            for (int g = 0; g < 4; ++g) {
                int tile = g * 16 + w;
                bf16x8 bfr = *(const bf16x8*)(Bp + ((size_t)(tile * 9 + kk) * 64 + l) * 8);
                acc[g] = __builtin_amdgcn_mfma_f32_16x16x32_bf16(a, bfr, acc[g], 0, 0, 0);
            }
        }
        __syncthreads();  // all A_sh reads done before overwrite

        // epilogue, fully in-register: lane holds i,f,g,o for 4 batches at column m
#pragma unroll
        for (int r = 0; r < 4; ++r) {
            float ig = acc[0][r], fg = acc[1][r], gg = acc[2][r], og = acc[3][r];
            float cn = sigf(fg) * c[r] + sigf(ig) * tanhfast(gg);
            c[r] = cn;
            float h = sigf(og) * tanhfast(cn);
            int b = kg * 4 + r;
            A_sh[b * STRA + m] = f2bf(h);
            if (t == SEQLEN - 1)
                h1bf[((size_t)s * NB + b) * NH + m] = f2bf(h);
        }
        if (t + 1 < SEQLEN && tid < NB * NIN)
            A_sh[xb * STRA + NH + xk] = f2bf(xpre);
        __syncthreads();
    }
}

// ---------------- Layer 2: 32-step LSTM over per-sequence hiddens + final linear ----------------
#define STRA2 520  // 512 data + 8 pad

__global__ __launch_bounds__(1024) void lstm_layer2(
    const unsigned short* __restrict__ h1bf,
    const float* __restrict__ bih2, const float* __restrict__ bhh2,
    const unsigned short* __restrict__ Bp2,
    const float* __restrict__ Wlin, const float* __restrict__ blin,
    float* __restrict__ out) {
    __shared__ __align__(16) unsigned short A_sh[NB * STRA2];  // [h2(256) | h1_s(256)]
    __shared__ float hf[NB * NH];
    __shared__ float red[NB * 16];

    const int tid = threadIdx.x;
    const int w = tid >> 6, l = tid & 63, lr = l & 15, kg = l >> 4;
    const int m = w * 16 + lr;

    float bias[4];
#pragma unroll
    for (int g = 0; g < 4; ++g)
        bias[g] = bih2[g * NH + m] + bhh2[g * NH + m];
    float c[4] = {0.f, 0.f, 0.f, 0.f};

    for (int i = tid; i < NB * NH; i += 1024)
        A_sh[(i >> 8) * STRA2 + (i & 255)] = 0;
    // stage h1[0] into x-part
    const int sb = tid >> 6, sm4 = (tid & 63) * 4;
    {
        const unsigned short* src = h1bf + (size_t)sb * NH + sm4;
#pragma unroll
        for (int j = 0; j < 4; ++j) A_sh[sb * STRA2 + NH + sm4 + j] = src[j];
    }
    __syncthreads();

    for (int s = 0; s < NSEQ; ++s) {
        unsigned short pre[4];
        if (s + 1 < NSEQ) {
            const unsigned short* src = h1bf + ((size_t)(s + 1) * NB + sb) * NH + sm4;
#pragma unroll
            for (int j = 0; j < 4; ++j) pre[j] = src[j];
        }

        f32x4 acc[4];
#pragma unroll
        for (int g = 0; g < 4; ++g) { f32x4 v = {bias[g], bias[g], bias[g], bias[g]}; acc[g] = v; }

#pragma unroll
        for (int kk = 0; kk < 16; ++kk) {
            bf16x8 a = *(const bf16x8*)&A_sh[lr * STRA2 + kk * 32 + kg * 8];
#pragma unroll
            for (int g = 0; g < 4; ++g) {
                int tile = g * 16 + w;
                bf16x8 bfr = *(const bf16x8*)(Bp2 + ((size_t)(tile * 16 + kk) * 64 + l) * 8);
                acc[g] = __builtin_amdgcn_mfma_f32_16x16x32_bf16(a, bfr, acc[g], 0, 0, 0);
            }
        }
        __syncthreads();

#pragma unroll
        for (int r = 0; r < 4; ++r) {
            float ig = acc[0][r], fg = acc[1][r], gg = acc[2][r], og = acc[3][r];
            float cn = sigf(fg) * c[r] + sigf(ig) * tanhfast(gg);
            c[r] = cn;
            float h = sigf(og) * tanhfast(cn);
            int b = kg * 4 + r;
            A_sh[b * STRA2 + m] = f2bf(h);
            if (s == NSEQ - 1) hf[b * NH + m] = h;
        }
        if (s + 1 < NSEQ) {
#pragma unroll
            for (int j = 0; j < 4; ++j) A_sh[sb * STRA2 + NH + sm4 + j] = pre[j];
        }
        __syncthreads();
    }

    // final: out[b] = sigmoid(h2[b] . Wlin + blin)
    if (tid < 256) {
        int b = tid >> 4, kc = tid & 15;
        float p = 0.f;
#pragma unroll
        for (int k = 0; k < 16; ++k) p += hf[b * NH + kc * 16 + k] * Wlin[kc * 16 + k];
        red[b * 16 + kc] = p;
    }
    __syncthreads();
    if (tid < 16) {
        float ssum = blin[0];
#pragma unroll
        for (int kc = 0; kc < 16; ++kc) ssum += red[tid * 16 + kc];
        out[tid] = 1.0f / (1.0f + __expf(-ssum));
    }
}

// ---------------- host ----------------
extern "C" void kernel_launch(void* const* d_in, const int* in_sizes, int n_in,
                              void* d_out, int out_size, void* d_ws, size_t ws_size,
                              hipStream_t stream) {
    const float* x    = (const float*)d_in[0];
    const int*   flg  = (const int*)d_in[1];
    const float* Wih1 = (const float*)d_in[2];
    const float* Whh1 = (const float*)d_in[3];
    const float* bih1 = (const float*)d_in[4];
    const float* bhh1 = (const float*)d_in[5];
    const float* Wih2 = (const float*)d_in[6];
    const float* Whh2 = (const float*)d_in[7];
    const float* bih2 = (const float*)d_in[8];
    const float* bhh2 = (const float*)d_in[9];
    const float* Wlin = (const float*)d_in[10];
    const float* blin = (const float*)d_in[11];
    float* out = (float*)d_out;

    // workspace layout (bf16 units): Bp1 | Bp2 | h1bf  (~2.4 MB total)
    unsigned short* ws   = (unsigned short*)d_ws;
    unsigned short* Bp1  = ws;                     // 2*64*9*64*8  = 589824
    unsigned short* Bp2  = Bp1 + 589824;           // 64*16*64*8   = 524288
    unsigned short* h1bf = Bp2 + 524288;           // 32*16*256    = 131072

    pack_w1<<<dim3(288), dim3(256), 0, stream>>>(Wih1, Whh1, Bp1);
    pack_w2<<<dim3(256), dim3(256), 0, stream>>>(Wih2, Whh2, Bp2);
    lstm_layer1<<<dim3(32), dim3(1024), 0, stream>>>(x, flg, bih1, bhh1, Bp1, h1bf);
    lstm_layer2<<<dim3(1), dim3(1024), 0, stream>>>(h1bf, bih2, bhh2, Bp2, Wlin, blin, out);
}

// Round 2
// 2123.487 us; speedup vs baseline: 1.5949x; 1.5949x over previous
//
#include <hip/hip_runtime.h>
#include <hip/hip_bf16.h>

// Sizes from the reference
#define NSEQ   32
#define SEQLEN 256
#define NB     16    // batch
#define NIN    32
#define NH     256
#define G4     1024  // 4*H

#define CNT_STRIDE 32  // pad counters to 128B lines to avoid cross-XCD ping-pong

typedef __attribute__((ext_vector_type(8))) short bf16x8;
typedef __attribute__((ext_vector_type(4))) float f32x4;

__device__ __forceinline__ unsigned short f2bf(float f) {
    union { float f; unsigned u; } v; v.f = f;
    unsigned u = v.u;
    return (unsigned short)((u + 0x7FFFu + ((u >> 16) & 1u)) >> 16);  // RNE
}
__device__ __forceinline__ float bf2f(unsigned short u) {
    union { unsigned u; float f; } v; v.u = ((unsigned)u) << 16; return v.f;
}
__device__ __forceinline__ float sigf(float x) { return 1.0f / (1.0f + __expf(-x)); }
__device__ __forceinline__ float tanhfast(float x) { return 1.0f - 2.0f / (__expf(2.0f * x) + 1.0f); }

// ---------------- Prologue: pack weights into MFMA B-fragment layout ----------------
// (also zeroes the inter-block sync counters each launch/replay)
__global__ void pack_w1(const float* __restrict__ Wih, const float* __restrict__ Whh,
                        unsigned short* __restrict__ Bp, unsigned int* __restrict__ cnt) {
    if (blockIdx.x == 0 && threadIdx.x < 33 * CNT_STRIDE && (threadIdx.x % CNT_STRIDE) == 0)
        cnt[threadIdx.x] = 0;
    int idx = blockIdx.x * blockDim.x + threadIdx.x;
    if (idx >= 2 * 64 * 9 * 64) return;
    int fl   = idx / (64 * 9 * 64);
    int rem  = idx % (64 * 9 * 64);
    int tile = rem / (9 * 64);
    int kk   = (rem / 64) % 9;
    int l    = idx & 63;
    int n    = tile * 16 + (l & 15);
    int k0   = kk * 32 + (l >> 4) * 8;
    unsigned short* dst = Bp + (size_t)idx * 8;
#pragma unroll
    for (int j = 0; j < 8; ++j) {
        int k = k0 + j;
        float v = (k < NH) ? Whh[((size_t)fl * G4 + n) * NH + k]
                           : Wih[((size_t)fl * G4 + n) * NIN + (k - NH)];
        dst[j] = f2bf(v);
    }
}

__global__ void pack_w2(const float* __restrict__ Wih, const float* __restrict__ Whh,
                        unsigned short* __restrict__ Bp) {
    int idx = blockIdx.x * blockDim.x + threadIdx.x;
    if (idx >= 64 * 16 * 64) return;
    int tile = idx / (16 * 64);
    int kk   = (idx / 64) % 16;
    int l    = idx & 63;
    int n    = tile * 16 + (l & 15);
    int k0   = kk * 32 + (l >> 4) * 8;
    unsigned short* dst = Bp + (size_t)idx * 8;
#pragma unroll
    for (int j = 0; j < 8; ++j) {
        int k = k0 + j;
        float v = (k < NH) ? Whh[(size_t)n * NH + k] : Wih[(size_t)n * NH + (k - NH)];
        dst[j] = f2bf(v);
    }
}

// ---------------- Layer 1: 4 blocks per sequence, weights resident in VGPRs ----------------
// bid = j*32 + s  -> the 4 blocks of sequence s share XCD (s%8)  [perf-only heuristic]
// Block (s,j) owns hidden columns j*64..j*64+63. Wave w: gate g=w>>2, colgroup cg=w&3,
// global tile = g*16 + j*4 + cg; holds that tile's 9 K-fragments in registers (36 VGPR).
#define STRA 296  // A_sh row stride (288 data + 8 pad)

__global__ __launch_bounds__(1024, 4) void lstm_layer1(
    const float* __restrict__ x, const int* __restrict__ flags,
    const float* __restrict__ bih, const float* __restrict__ bhh,
    const unsigned short* __restrict__ Bp_all,
    unsigned short* __restrict__ h1bf,
    unsigned short* __restrict__ hx,        // [2][NSEQ][NB][NH] bf16 double-buffered h exchange
    unsigned int* __restrict__ cnt) {       // [NSEQ] stride CNT_STRIDE arrival counters
    __shared__ __align__(16) unsigned short A_sh[NB * STRA];  // [h(256) | x(32)] per batch row
    __shared__ float gate_sh[4][64][19];                      // [gate][local col][batch], pad 19

    const int bid = blockIdx.x;
    const int s   = bid & 31;
    const int j   = bid >> 5;
    const int tid = threadIdx.x;
    const int w = tid >> 6, l = tid & 63, lr = l & 15, kg = l >> 4;
    const int g = w >> 2, cg = w & 3;
    const int fl = flags[s];
    const int tile = g * 16 + j * 4 + cg;
    const unsigned short* Bp = Bp_all + (size_t)fl * (64 * 9 * 64 * 8);

    // weights -> registers, once
    bf16x8 wreg[9];
#pragma unroll
    for (int kk = 0; kk < 9; ++kk)
        wreg[kk] = *(const bf16x8*)(Bp + ((size_t)(tile * 9 + kk) * 64 + l) * 8);

    const int grow = tile * 16 + lr;
    const float bias = bih[fl * G4 + grow] + bhh[fl * G4 + grow];

    const int eb = tid >> 6, ec = tid & 63;     // epilogue: (batch, local col)
    float cst = 0.f;                            // cell state, per thread

    for (int i = tid; i < NB * NH; i += 1024)
        A_sh[(i >> 8) * STRA + (i & 255)] = 0;
    if (tid < NB * NIN) {
        int b = tid >> 5, k = tid & 31;
        A_sh[b * STRA + NH + k] = f2bf(x[((size_t)(s * SEQLEN) * NB + b) * NIN + k]);
    }
    __syncthreads();

    const int xb = tid >> 5, xk = tid & 31;
    const int rb = tid >> 6, rc = (tid & 63) * 4;   // readback mapping
    unsigned int* mycnt = cnt + s * CNT_STRIDE;

    for (int t = 0; t < SEQLEN; ++t) {
        float xpre = 0.f;
        if (t + 1 < SEQLEN && tid < NB * NIN)
            xpre = x[((size_t)(s * SEQLEN + t + 1) * NB + xb) * NIN + xk];

        f32x4 acc = {bias, bias, bias, bias};
#pragma unroll
        for (int kk = 0; kk < 9; ++kk) {
            bf16x8 a = *(const bf16x8*)&A_sh[lr * STRA + kk * 32 + kg * 8];
            acc = __builtin_amdgcn_mfma_f32_16x16x32_bf16(a, wreg[kk], acc, 0, 0, 0);
        }
#pragma unroll
        for (int r = 0; r < 4; ++r)
            gate_sh[g][cg * 16 + lr][kg * 4 + r] = acc[r];
        __syncthreads();

        float ig = gate_sh[0][ec][eb], fg = gate_sh[1][ec][eb];
        float gg = gate_sh[2][ec][eb], og = gate_sh[3][ec][eb];
        float cn = sigf(fg) * cst + sigf(ig) * tanhfast(gg);
        cst = cn;
        float h = sigf(og) * tanhfast(cn);
        unsigned short hbf = f2bf(h);

        if (t == SEQLEN - 1) {
            h1bf[((size_t)s * NB + eb) * NH + j * 64 + ec] = hbf;
        } else {
            const int p = (t + 1) & 1;
            hx[(((size_t)p * NSEQ + s) * NB + eb) * NH + j * 64 + ec] = hbf;
            __syncthreads();  // drains vmcnt: all block stores complete
            if (tid == 0) {
                __threadfence();  // device-scope release of h stores
                __hip_atomic_fetch_add(mycnt, 1u, __ATOMIC_RELEASE, __HIP_MEMORY_SCOPE_AGENT);
                const unsigned tgt = 4u * (unsigned)(t + 1);
                while (__hip_atomic_load(mycnt, __ATOMIC_ACQUIRE, __HIP_MEMORY_SCOPE_AGENT) < tgt)
                    __builtin_amdgcn_s_sleep(1);
                __threadfence();  // acquire: invalidate caches before data reads
            }
            __syncthreads();
            *(ushort4*)&A_sh[rb * STRA + rc] =
                *(const ushort4*)&hx[(((size_t)p * NSEQ + s) * NB + rb) * NH + rc];
            if (tid < NB * NIN)
                A_sh[xb * STRA + NH + xk] = f2bf(xpre);
            __syncthreads();
        }
    }
}

// ---------------- Layer 2: 4 blocks, 32-step scan over h1, weights in VGPRs ----------------
// grid=32, only bid%8==0 active -> 4 active blocks all map to XCD 0 (perf-only).
#define STRA2 520  // 512 data + 8 pad

__global__ __launch_bounds__(1024, 4) void lstm_layer2(
    const unsigned short* __restrict__ h1bf,
    const float* __restrict__ bih2, const float* __restrict__ bhh2,
    const unsigned short* __restrict__ Bp2,
    const float* __restrict__ Wlin, const float* __restrict__ blin,
    float* __restrict__ out,
    unsigned short* __restrict__ hx2,       // [2][NB][NH]
    unsigned int* __restrict__ cnt2) {
    const int bid = blockIdx.x;
    if (bid & 7) return;
    const int j = bid >> 3;

    __shared__ __align__(16) unsigned short A_sh[NB * STRA2];  // [h2(256) | h1_s(256)]
    __shared__ float gate_sh[4][64][19];
    __shared__ float red[NB * 16];

    const int tid = threadIdx.x;
    const int w = tid >> 6, l = tid & 63, lr = l & 15, kg = l >> 4;
    const int g = w >> 2, cg = w & 3;
    const int tile = g * 16 + j * 4 + cg;

    bf16x8 wreg[16];
#pragma unroll
    for (int kk = 0; kk < 16; ++kk)
        wreg[kk] = *(const bf16x8*)(Bp2 + ((size_t)(tile * 16 + kk) * 64 + l) * 8);

    const int grow = tile * 16 + lr;
    const float bias = bih2[grow] + bhh2[grow];
    const int eb = tid >> 6, ec = tid & 63;
    float cst = 0.f;
    const int rb = tid >> 6, rc = (tid & 63) * 4;

    for (int i = tid; i < NB * NH; i += 1024)
        A_sh[(i >> 8) * STRA2 + (i & 255)] = 0;
    *(ushort4*)&A_sh[rb * STRA2 + NH + rc] = *(const ushort4*)&h1bf[(size_t)rb * NH + rc];
    __syncthreads();

    for (int sq = 0; sq < NSEQ; ++sq) {
        ushort4 pre = {0, 0, 0, 0};
        if (sq + 1 < NSEQ)
            pre = *(const ushort4*)&h1bf[((size_t)(sq + 1) * NB + rb) * NH + rc];

        f32x4 acc = {bias, bias, bias, bias};
#pragma unroll
        for (int kk = 0; kk < 16; ++kk) {
            bf16x8 a = *(const bf16x8*)&A_sh[lr * STRA2 + kk * 32 + kg * 8];
            acc = __builtin_amdgcn_mfma_f32_16x16x32_bf16(a, wreg[kk], acc, 0, 0, 0);
        }
#pragma unroll
        for (int r = 0; r < 4; ++r)
            gate_sh[g][cg * 16 + lr][kg * 4 + r] = acc[r];
        __syncthreads();

        float ig = gate_sh[0][ec][eb], fg = gate_sh[1][ec][eb];
        float gg = gate_sh[2][ec][eb], og = gate_sh[3][ec][eb];
        float cn = sigf(fg) * cst + sigf(ig) * tanhfast(gg);
        cst = cn;
        float h = sigf(og) * tanhfast(cn);
        const int p = (sq + 1) & 1;
        hx2[((size_t)p * NB + eb) * NH + j * 64 + ec] = f2bf(h);
        __syncthreads();
        if (tid == 0) {
            __threadfence();
            __hip_atomic_fetch_add(cnt2, 1u, __ATOMIC_RELEASE, __HIP_MEMORY_SCOPE_AGENT);
            const unsigned tgt = 4u * (unsigned)(sq + 1);
            while (__hip_atomic_load(cnt2, __ATOMIC_ACQUIRE, __HIP_MEMORY_SCOPE_AGENT) < tgt)
                __builtin_amdgcn_s_sleep(1);
            __threadfence();
        }
        __syncthreads();
        *(ushort4*)&A_sh[rb * STRA2 + rc] =
            *(const ushort4*)&hx2[((size_t)p * NB + rb) * NH + rc];
        if (sq + 1 < NSEQ)
            *(ushort4*)&A_sh[rb * STRA2 + NH + rc] = pre;
        __syncthreads();
    }

    // final linear + sigmoid, block j==0 only (A_sh h-part holds full h2_32)
    if (j == 0) {
        if (tid < 256) {
            int b = tid >> 4, kc = tid & 15;
            float pacc = 0.f;
#pragma unroll
            for (int k = 0; k < 16; ++k)
                pacc += bf2f(A_sh[b * STRA2 + kc * 16 + k]) * Wlin[kc * 16 + k];
            red[b * 16 + kc] = pacc;
        }
        __syncthreads();
        if (tid < 16) {
            float ssum = blin[0];
#pragma unroll
            for (int kc = 0; kc < 16; ++kc) ssum += red[tid * 16 + kc];
            out[tid] = 1.0f / (1.0f + __expf(-ssum));
        }
    }
}

// ---------------- host ----------------
extern "C" void kernel_launch(void* const* d_in, const int* in_sizes, int n_in,
                              void* d_out, int out_size, void* d_ws, size_t ws_size,
                              hipStream_t stream) {
    const float* x    = (const float*)d_in[0];
    const int*   flg  = (const int*)d_in[1];
    const float* Wih1 = (const float*)d_in[2];
    const float* Whh1 = (const float*)d_in[3];
    const float* bih1 = (const float*)d_in[4];
    const float* bhh1 = (const float*)d_in[5];
    const float* Wih2 = (const float*)d_in[6];
    const float* Whh2 = (const float*)d_in[7];
    const float* bih2 = (const float*)d_in[8];
    const float* bhh2 = (const float*)d_in[9];
    const float* Wlin = (const float*)d_in[10];
    const float* blin = (const float*)d_in[11];
    float* out = (float*)d_out;

    // workspace layout (ushort units)
    unsigned short* ws   = (unsigned short*)d_ws;
    unsigned short* Bp1  = ws;                     // 2*64*9*64*8  = 589824
    unsigned short* Bp2  = Bp1 + 589824;           // 64*16*64*8   = 524288
    unsigned short* h1bf = Bp2 + 524288;           // 32*16*256    = 131072
    unsigned short* hx1  = h1bf + 131072;          // 2*32*16*256  = 262144
    unsigned short* hx2  = hx1 + 262144;           // 2*16*256     = 8192
    unsigned int*   cnt  = (unsigned int*)(hx2 + 8192);  // 33*CNT_STRIDE uints
    unsigned int*   cnt2 = cnt + 32 * CNT_STRIDE;

    pack_w1<<<dim3(288), dim3(256), 0, stream>>>(Wih1, Whh1, Bp1, cnt);
    pack_w2<<<dim3(256), dim3(256), 0, stream>>>(Wih2, Whh2, Bp2);
    lstm_layer1<<<dim3(128), dim3(1024), 0, stream>>>(x, flg, bih1, bhh1, Bp1, h1bf, hx1, cnt);
    lstm_layer2<<<dim3(32), dim3(1024), 0, stream>>>(h1bf, bih2, bhh2, Bp2, Wlin, blin, out, hx2, cnt2);
}

// Round 3
// 756.638 us; speedup vs baseline: 4.4759x; 2.8065x over previous
//
#include <hip/hip_runtime.h>
#include <hip/hip_bf16.h>

// Sizes from the reference
#define NSEQ   32
#define SEQLEN 256
#define NB     16    // batch
#define NIN    32
#define NH     256
#define G4     1024  // 4*H

#define CNT_STRIDE 32  // pad counters to 128B lines

typedef __attribute__((ext_vector_type(8))) short bf16x8;
typedef __attribute__((ext_vector_type(4))) float f32x4;
typedef unsigned long long ull;

__device__ __forceinline__ unsigned short f2bf(float f) {
    union { float f; unsigned u; } v; v.f = f;
    unsigned u = v.u;
    return (unsigned short)((u + 0x7FFFu + ((u >> 16) & 1u)) >> 16);  // RNE
}
__device__ __forceinline__ float bf2f(unsigned short u) {
    union { unsigned u; float f; } v; v.u = ((unsigned)u) << 16; return v.f;
}
__device__ __forceinline__ float sigf(float x) { return 1.0f / (1.0f + __expf(-x)); }
__device__ __forceinline__ float tanhfast(float x) { return 1.0f - 2.0f / (__expf(2.0f * x) + 1.0f); }

// ---------------- Prologue: pack weights into MFMA B-fragment layout ----------------
// Also zeroes ALL sync counters each launch/replay (33*CNT_STRIDE uints).
__global__ void pack_w1(const float* __restrict__ Wih, const float* __restrict__ Whh,
                        unsigned short* __restrict__ Bp, unsigned int* __restrict__ cnt) {
    int idx = blockIdx.x * blockDim.x + threadIdx.x;
    if (idx < 33 * CNT_STRIDE) cnt[idx] = 0;
    if (idx >= 2 * 64 * 9 * 64) return;
    int fl   = idx / (64 * 9 * 64);
    int rem  = idx % (64 * 9 * 64);
    int tile = rem / (9 * 64);
    int kk   = (rem / 64) % 9;
    int l    = rem & 63;
    int n    = tile * 16 + (l & 15);
    int k0   = kk * 32 + (l >> 4) * 8;
    unsigned short* dst = Bp + (size_t)idx * 8;
#pragma unroll
    for (int j = 0; j < 8; ++j) {
        int k = k0 + j;
        float v = (k < NH) ? Whh[((size_t)fl * G4 + n) * NH + k]
                           : Wih[((size_t)fl * G4 + n) * NIN + (k - NH)];
        dst[j] = f2bf(v);
    }
}

__global__ void pack_w2(const float* __restrict__ Wih, const float* __restrict__ Whh,
                        unsigned short* __restrict__ Bp) {
    int idx = blockIdx.x * blockDim.x + threadIdx.x;
    if (idx >= 64 * 16 * 64) return;
    int tile = idx / (16 * 64);
    int kk   = (idx / 64) % 16;
    int l    = idx & 63;
    int n    = tile * 16 + (l & 15);
    int k0   = kk * 32 + (l >> 4) * 8;
    unsigned short* dst = Bp + (size_t)idx * 8;
#pragma unroll
    for (int j = 0; j < 8; ++j) {
        int k = k0 + j;
        float v = (k < NH) ? Whh[(size_t)n * NH + k] : Wih[(size_t)n * NH + (k - NH)];
        dst[j] = f2bf(v);
    }
}

// ---------------- Layer 1: 4 blocks/sequence, weights in regs, MALL-based sync ----------------
// bid = j*32 + s. Block (s,j) owns hidden cols j*64..j*64+63. Wave w: gate g=w>>2,
// colgroup cg=w&3, tile = g*16 + j*4 + cg (9 K-fragments resident in registers).
// Exchange protocol (no fences): relaxed AGENT atomics only; release = the
// vmcnt(0) drain __syncthreads performs; acquire = sc0sc1 loads bypass stale caches.
#define STRA 296  // A_sh row stride (288 data + 8 pad)

__global__ __launch_bounds__(1024, 4) void lstm_layer1(
    const float* __restrict__ x, const int* __restrict__ flags,
    const float* __restrict__ bih, const float* __restrict__ bhh,
    const unsigned short* __restrict__ Bp_all,
    unsigned short* __restrict__ h1bf,
    ull* __restrict__ hx,                    // [2][NSEQ][NB][64] ull (4 bf16 each)
    unsigned int* __restrict__ cnt) {
    __shared__ __align__(16) unsigned short A_sh[NB * STRA];  // [h(256)|x(32)] per batch
    __shared__ float gate_sh[4][64][19];

    const int bid = blockIdx.x;
    const int s   = bid & 31;
    const int j   = bid >> 5;
    const int tid = threadIdx.x;
    const int w = tid >> 6, l = tid & 63, lr = l & 15, kg = l >> 4;
    const int g = w >> 2, cg = w & 3;
    const int fl = flags[s];
    const int tile = g * 16 + j * 4 + cg;
    const unsigned short* Bp = Bp_all + (size_t)fl * (64 * 9 * 64 * 8);

    bf16x8 wreg[9];
#pragma unroll
    for (int kk = 0; kk < 9; ++kk)
        wreg[kk] = *(const bf16x8*)(Bp + ((size_t)(tile * 9 + kk) * 64 + l) * 8);

    const int grow = tile * 16 + lr;
    const float bias = bih[fl * G4 + grow] + bhh[fl * G4 + grow];

    // epilogue/pack mapping: 256 threads, each (batch pb, 4 cols starting j*64+pq*4)
    const int pb = tid >> 4, pq = tid & 15;
    float cst[4] = {0.f, 0.f, 0.f, 0.f};

    // readback mapping: (batch rb, ull-index rq over all 256 cols)
    const int rb = tid >> 6, rq = tid & 63;
    const bool rother = (rq >> 4) != j;
    const int xb = tid >> 5, xk = tid & 31;
    unsigned int* mycnt = cnt + s * CNT_STRIDE;

    for (int i = tid; i < NB * NH; i += 1024)
        A_sh[(i >> 8) * STRA + (i & 255)] = 0;
    if (tid < NB * NIN)
        A_sh[xb * STRA + NH + xk] = f2bf(x[((size_t)(s * SEQLEN) * NB + xb) * NIN + xk]);
    __syncthreads();

    for (int t = 0; t < SEQLEN; ++t) {
        float xpre = 0.f;
        if (t + 1 < SEQLEN && tid < NB * NIN)
            xpre = x[((size_t)(s * SEQLEN + t + 1) * NB + xb) * NIN + xk];

        f32x4 acc = {bias, bias, bias, bias};
#pragma unroll
        for (int kk = 0; kk < 9; ++kk) {
            bf16x8 a = *(const bf16x8*)&A_sh[lr * STRA + kk * 32 + kg * 8];
            acc = __builtin_amdgcn_mfma_f32_16x16x32_bf16(a, wreg[kk], acc, 0, 0, 0);
        }
#pragma unroll
        for (int r = 0; r < 4; ++r)
            gate_sh[g][cg * 16 + lr][kg * 4 + r] = acc[r];
        __syncthreads();  // B1: gates ready, all A_sh reads done

        const int p = (t + 1) & 1;
        if (tid < 256) {
            ull wv = 0;
#pragma unroll
            for (int r = 0; r < 4; ++r) {
                const int c = pq * 4 + r;
                float ig = gate_sh[0][c][pb], fg = gate_sh[1][c][pb];
                float gg = gate_sh[2][c][pb], og = gate_sh[3][c][pb];
                float cn = sigf(fg) * cst[r] + sigf(ig) * tanhfast(gg);
                cst[r] = cn;
                float h = sigf(og) * tanhfast(cn);
                wv |= ((ull)f2bf(h)) << (16 * r);
            }
            *(ull*)&A_sh[pb * STRA + j * 64 + pq * 4] = wv;  // own cols -> LDS directly
            if (t == SEQLEN - 1)
                *(ull*)&h1bf[((size_t)s * NB + pb) * NH + j * 64 + pq * 4] = wv;
            else
                __hip_atomic_store(&hx[(((size_t)p * NSEQ + s) * NB + pb) * 64 + j * 16 + pq],
                                   wv, __ATOMIC_RELAXED, __HIP_MEMORY_SCOPE_AGENT);
        }
        if (t < SEQLEN - 1) {
            __syncthreads();  // B2: drains vmcnt(0) -> hx stores visible at MALL
            if (tid == 0) {
                __hip_atomic_fetch_add(mycnt, 1u, __ATOMIC_RELAXED, __HIP_MEMORY_SCOPE_AGENT);
                const unsigned tgt = 4u * (unsigned)(t + 1);
                while (__hip_atomic_load(mycnt, __ATOMIC_RELAXED, __HIP_MEMORY_SCOPE_AGENT) < tgt) {}
            }
            __syncthreads();  // B3
            if (rother) {
                ull wv = __hip_atomic_load(&hx[(((size_t)p * NSEQ + s) * NB + rb) * 64 + rq],
                                           __ATOMIC_RELAXED, __HIP_MEMORY_SCOPE_AGENT);
                *(ull*)&A_sh[rb * STRA + rq * 4] = wv;
            }
            if (tid < NB * NIN)
                A_sh[xb * STRA + NH + xk] = f2bf(xpre);
            __syncthreads();  // B4
        }
    }
}

// ---------------- Layer 2: 4 blocks, 32-step scan, same protocol ----------------
#define STRA2 520  // 512 data + 8 pad

__global__ __launch_bounds__(1024, 4) void lstm_layer2(
    const unsigned short* __restrict__ h1bf,
    const float* __restrict__ bih2, const float* __restrict__ bhh2,
    const unsigned short* __restrict__ Bp2,
    const float* __restrict__ Wlin, const float* __restrict__ blin,
    float* __restrict__ out,
    ull* __restrict__ hx2,                   // [2][NB][64] ull
    unsigned int* __restrict__ cnt2) {
    const int bid = blockIdx.x;
    if (bid & 7) return;
    const int j = bid >> 3;

    __shared__ __align__(16) unsigned short A_sh[NB * STRA2];  // [h2(256)|h1_s(256)]
    __shared__ float gate_sh[4][64][19];
    __shared__ float red[NB * 16];

    const int tid = threadIdx.x;
    const int w = tid >> 6, l = tid & 63, lr = l & 15, kg = l >> 4;
    const int g = w >> 2, cg = w & 3;
    const int tile = g * 16 + j * 4 + cg;

    bf16x8 wreg[16];
#pragma unroll
    for (int kk = 0; kk < 16; ++kk)
        wreg[kk] = *(const bf16x8*)(Bp2 + ((size_t)(tile * 16 + kk) * 64 + l) * 8);

    const int grow = tile * 16 + lr;
    const float bias = bih2[grow] + bhh2[grow];
    const int pb = tid >> 4, pq = tid & 15;
    float cst[4] = {0.f, 0.f, 0.f, 0.f};
    const int rb = tid >> 6, rq = tid & 63;
    const bool rother = (rq >> 4) != j;

    for (int i = tid; i < NB * NH; i += 1024)
        A_sh[(i >> 8) * STRA2 + (i & 255)] = 0;
    *(ushort4*)&A_sh[rb * STRA2 + NH + rq * 4] = *(const ushort4*)&h1bf[(size_t)rb * NH + rq * 4];
    __syncthreads();

    for (int sq = 0; sq < NSEQ; ++sq) {
        ushort4 pre = {0, 0, 0, 0};
        if (sq + 1 < NSEQ)
            pre = *(const ushort4*)&h1bf[((size_t)(sq + 1) * NB + rb) * NH + rq * 4];

        f32x4 acc = {bias, bias, bias, bias};
#pragma unroll
        for (int kk = 0; kk < 16; ++kk) {
            bf16x8 a = *(const bf16x8*)&A_sh[lr * STRA2 + kk * 32 + kg * 8];
            acc = __builtin_amdgcn_mfma_f32_16x16x32_bf16(a, wreg[kk], acc, 0, 0, 0);
        }
#pragma unroll
        for (int r = 0; r < 4; ++r)
            gate_sh[g][cg * 16 + lr][kg * 4 + r] = acc[r];
        __syncthreads();  // B1

        const int p = (sq + 1) & 1;
        if (tid < 256) {
            ull wv = 0;
#pragma unroll
            for (int r = 0; r < 4; ++r) {
                const int c = pq * 4 + r;
                float ig = gate_sh[0][c][pb], fg = gate_sh[1][c][pb];
                float gg = gate_sh[2][c][pb], og = gate_sh[3][c][pb];
                float cn = sigf(fg) * cst[r] + sigf(ig) * tanhfast(gg);
                cst[r] = cn;
                float h = sigf(og) * tanhfast(cn);
                wv |= ((ull)f2bf(h)) << (16 * r);
            }
            *(ull*)&A_sh[pb * STRA2 + j * 64 + pq * 4] = wv;
            __hip_atomic_store(&hx2[((size_t)p * NB + pb) * 64 + j * 16 + pq],
                               wv, __ATOMIC_RELAXED, __HIP_MEMORY_SCOPE_AGENT);
        }
        __syncthreads();  // B2: drain
        if (tid == 0) {
            __hip_atomic_fetch_add(cnt2, 1u, __ATOMIC_RELAXED, __HIP_MEMORY_SCOPE_AGENT);
            const unsigned tgt = 4u * (unsigned)(sq + 1);
            while (__hip_atomic_load(cnt2, __ATOMIC_RELAXED, __HIP_MEMORY_SCOPE_AGENT) < tgt) {}
        }
        __syncthreads();  // B3
        if (rother) {
            ull wv = __hip_atomic_load(&hx2[((size_t)p * NB + rb) * 64 + rq],
                                       __ATOMIC_RELAXED, __HIP_MEMORY_SCOPE_AGENT);
            *(ull*)&A_sh[rb * STRA2 + rq * 4] = wv;
        }
        if (sq + 1 < NSEQ)
            *(ushort4*)&A_sh[rb * STRA2 + NH + rq * 4] = pre;
        __syncthreads();  // B4
    }

    // final linear + sigmoid, block 0 (A_sh h-part now holds full final h2)
    if (j == 0) {
        if (tid < 256) {
            int b = tid >> 4, kc = tid & 15;
            float pacc = 0.f;
#pragma unroll
            for (int k = 0; k < 16; ++k)
                pacc += bf2f(A_sh[b * STRA2 + kc * 16 + k]) * Wlin[kc * 16 + k];
            red[b * 16 + kc] = pacc;
        }
        __syncthreads();
        if (tid < 16) {
            float ssum = blin[0];
#pragma unroll
            for (int kc = 0; kc < 16; ++kc) ssum += red[tid * 16 + kc];
            out[tid] = 1.0f / (1.0f + __expf(-ssum));
        }
    }
}

// ---------------- host ----------------
extern "C" void kernel_launch(void* const* d_in, const int* in_sizes, int n_in,
                              void* d_out, int out_size, void* d_ws, size_t ws_size,
                              hipStream_t stream) {
    const float* x    = (const float*)d_in[0];
    const int*   flg  = (const int*)d_in[1];
    const float* Wih1 = (const float*)d_in[2];
    const float* Whh1 = (const float*)d_in[3];
    const float* bih1 = (const float*)d_in[4];
    const float* bhh1 = (const float*)d_in[5];
    const float* Wih2 = (const float*)d_in[6];
    const float* Whh2 = (const float*)d_in[7];
    const float* bih2 = (const float*)d_in[8];
    const float* bhh2 = (const float*)d_in[9];
    const float* Wlin = (const float*)d_in[10];
    const float* blin = (const float*)d_in[11];
    float* out = (float*)d_out;

    // workspace layout (ushort units; all 8B-aligned)
    unsigned short* ws   = (unsigned short*)d_ws;
    unsigned short* Bp1  = ws;                     // 2*64*9*64*8  = 589824 ush
    unsigned short* Bp2  = Bp1 + 589824;           // 64*16*64*8   = 524288 ush
    unsigned short* h1bf = Bp2 + 524288;           // 32*16*256    = 131072 ush
    ull*            hx1  = (ull*)(h1bf + 131072);  // 2*32*16*64   = 65536 ull
    ull*            hx2  = hx1 + 65536;            // 2*16*64      = 2048 ull
    unsigned int*   cnt  = (unsigned int*)(hx2 + 2048);  // 33*CNT_STRIDE uints
    unsigned int*   cnt2 = cnt + 32 * CNT_STRIDE;

    pack_w1<<<dim3(288), dim3(256), 0, stream>>>(Wih1, Whh1, Bp1, cnt);
    pack_w2<<<dim3(256), dim3(256), 0, stream>>>(Wih2, Whh2, Bp2);
    lstm_layer1<<<dim3(128), dim3(1024), 0, stream>>>(x, flg, bih1, bhh1, Bp1, h1bf, hx1, cnt);
    lstm_layer2<<<dim3(32), dim3(1024), 0, stream>>>(h1bf, bih2, bhh2, Bp2, Wlin, blin, out, hx2, cnt2);
}